// Round 3
// baseline (122.412 us; speedup 1.0000x reference)
//
#include <hip/hip_runtime.h>
#include <math.h>

#define B_ 128
#define S_ 1024
#define D_ 256          // D == A == O == 256
#define XP 264          // LDS bf16 row pitch for x/v tile (528 B, 16B-aligned)
#define TP 68           // LDS fp32 row pitch for transpose buffer (272 B, 16B-aligned)
#define ROWS 32         // rows per block

using bf16x8 = __attribute__((ext_vector_type(8))) __bf16;
using bf16x4 = __attribute__((ext_vector_type(4))) __bf16;
using f32x4  = __attribute__((ext_vector_type(4))) float;

__device__ __forceinline__ float qred_add(float v) {   // reduce across 16-lane group
    v += __shfl_xor(v, 1); v += __shfl_xor(v, 2);
    v += __shfl_xor(v, 4); v += __shfl_xor(v, 8);
    return v;
}
__device__ __forceinline__ float wred_add(float x) {
#pragma unroll
    for (int off = 32; off > 0; off >>= 1) x += __shfl_xor(x, off, 64);
    return x;
}

// ---- prep: pack W, Uo (fp32 row-major [k][n]) into B-fragment-linear bf16.
__global__ __launch_bounds__(256) void k_prep(
    const float* __restrict__ W, const float* __restrict__ Uo,
    __bf16* __restrict__ Wf, __bf16* __restrict__ Uf)
{
    const int e = blockIdx.x * 256 + threadIdx.x;   // 0..65535
    const int frag = e >> 9, rem = e & 511;
    const int lane = rem >> 3, j = rem & 7;
    const int kk = frag >> 4, tn = frag & 15;
    const int k = kk * 32 + (lane >> 4) * 8 + j;
    const int n = tn * 16 + (lane & 15);
    Wf[e] = (__bf16)W[k * 256 + n];
    Uf[e] = (__bf16)Uo[k * 256 + n];
}

// ---- main fused kernel: 32 rows/block, 4 waves; wave w owns cols [64w, 64w+64).
// Single accumulator array reused by BOTH GEMMs (disjoint lifetimes) -> 32 AGPR
// not 64 -> total ~108 regs -> 4 blocks/CU at launch_bounds(256,4) without spill.
// (Round 0 spilled at (256,4) because both accumulator sets were live against
// the 128 cap: WRITE_SIZE 254 MB vs 135 MB true output. Watch WRITE_SIZE.)
__global__ __launch_bounds__(256, 4) void k_rows(
    const float* __restrict__ x, const float* __restrict__ mask,
    const __bf16* __restrict__ Wf, const float* __restrict__ bo,
    const float* __restrict__ u, const __bf16* __restrict__ Uf,
    float* __restrict__ e_out,    // [B*S] unnormalized exp(vu)*mask (alphas region)
    float* __restrict__ betas,    // [B*S, 256]
    float* __restrict__ part,     // [gridDim.x, 256] per-block out partials (ws)
    float* __restrict__ outraw,   // [B,256] atomic fallback accumulator
    const int use_part)
{
    // xs (bf16 x/v tile, 16896 B) aliased with trans (fp32 transpose buf, 17408 B)
    __shared__ __align__(16) char smem[4 * 16 * TP * 4];
    __bf16* xs   = (__bf16*)smem;
    float* trans = (float*)smem;
    __shared__ float red[4][ROWS];
    const int tid = threadIdx.x, lane = tid & 63, w = tid >> 6;
    const int quad = lane >> 4, c = lane & 15;
    const int hi = lane >> 4, c4 = lane & 15;      // store-phase decomposition
    const int row0 = blockIdx.x * ROWS;
    const bf16x8* Wf8 = (const bf16x8*)Wf;
    const bf16x8* Uf8 = (const bf16x8*)Uf;

    // stage x[32][256] fp32 -> bf16 LDS
    {
        const float4* xg = (const float4*)(x + (size_t)row0 * D_);
#pragma unroll
        for (int it = 0; it < 8; ++it) {
            const int r = it * 4 + w;
            const float4 t = xg[r * 64 + lane];
            bf16x4 h; h[0] = (__bf16)t.x; h[1] = (__bf16)t.y; h[2] = (__bf16)t.z; h[3] = (__bf16)t.w;
            *(bf16x4*)(xs + r * XP + lane * 4) = h;
        }
    }

    __syncthreads();                                   // sync0

    // ---- GEMM1: t = x @ W
    f32x4 acc[2][4];                                   // reused by GEMM2 (32 AGPR total)
#pragma unroll
    for (int i = 0; i < 2; ++i)
#pragma unroll
        for (int j = 0; j < 4; ++j) acc[i][j] = (f32x4){0.f, 0.f, 0.f, 0.f};
#pragma unroll
    for (int kk = 0; kk < 8; ++kk) {
        bf16x8 a[2], b[4];
#pragma unroll
        for (int i = 0; i < 2; ++i)
            a[i] = *(const bf16x8*)(xs + (i * 16 + c) * XP + kk * 32 + quad * 8);
#pragma unroll
        for (int j = 0; j < 4; ++j)
            b[j] = Wf8[(kk * 16 + w * 4 + j) * 64 + lane];
#pragma unroll
        for (int i = 0; i < 2; ++i)
#pragma unroll
            for (int j = 0; j < 4; ++j)
                acc[i][j] = __builtin_amdgcn_mfma_f32_16x16x32_bf16(a[i], b[j], acc[i][j], 0, 0, 0);
    }

    // bias + row sum-of-squares partials
#pragma unroll
    for (int j = 0; j < 4; ++j) {
        const float bj = bo[w * 64 + j * 16 + c];
#pragma unroll
        for (int i = 0; i < 2; ++i)
#pragma unroll
            for (int r = 0; r < 4; ++r) acc[i][j][r] += bj;
    }
    {
        float myv = 0.f;
#pragma unroll
        for (int i = 0; i < 2; ++i)
#pragma unroll
            for (int r = 0; r < 4; ++r) {
                float s = 0.f;
#pragma unroll
                for (int j = 0; j < 4; ++j) s += acc[i][j][r] * acc[i][j][r];
                const float p = qred_add(s);
                if (c == i * 4 + r) myv = p;
            }
        if (c < 8) red[w][(c >> 2) * 16 + quad * 4 + (c & 3)] = myv;
    }
    __syncthreads();                                   // (a)

    float inv[2][4];
#pragma unroll
    for (int i = 0; i < 2; ++i)
#pragma unroll
        for (int r = 0; r < 4; ++r) {
            const int row = i * 16 + quad * 4 + r;
            const float t = red[0][row] + red[1][row] + red[2][row] + red[3][row];
            inv[i][r] = 1.f / fmaxf(sqrtf(t), 1e-12f);
        }

    // v = tanh(t/||t||): vu partials, write v (bf16) into xs (reuse)
    // LAST read of GEMM1's acc -- it is dead after this loop (enables AGPR reuse).
    float uj[4];
#pragma unroll
    for (int j = 0; j < 4; ++j) uj[j] = u[w * 64 + j * 16 + c];
    float vup[2][4];
#pragma unroll
    for (int i = 0; i < 2; ++i)
#pragma unroll
        for (int r = 0; r < 4; ++r) vup[i][r] = 0.f;
#pragma unroll
    for (int i = 0; i < 2; ++i)
#pragma unroll
        for (int j = 0; j < 4; ++j)
#pragma unroll
            for (int r = 0; r < 4; ++r) {
                const float tv = acc[i][j][r] * inv[i][r];
                const float e2 = __expf(2.f * tv);
                const float v  = (e2 - 1.f) * __frcp_rn(e2 + 1.f);
                vup[i][r] += v * uj[j];
                xs[(i * 16 + quad * 4 + r) * XP + (w * 64 + j * 16 + c)] = (__bf16)v;
            }
    __syncthreads();                                   // (b) R1 reads + v writes done
    {
        float myv = 0.f;
#pragma unroll
        for (int i = 0; i < 2; ++i)
#pragma unroll
            for (int r = 0; r < 4; ++r) {
                const float p = qred_add(vup[i][r]);
                if (c == i * 4 + r) myv = p;
            }
        if (c < 8) red[w][(c >> 2) * 16 + quad * 4 + (c & 3)] = myv;
    }
    __syncthreads();                                   // (c) vu available in red

    // ev in store mapping: row r_ip = i*16 + hi + p*4
    float ev[2][4];
#pragma unroll
    for (int i = 0; i < 2; ++i)
#pragma unroll
        for (int p = 0; p < 4; ++p) {
            const int rr = i * 16 + hi + p * 4;
            const float vu = red[0][rr] + red[1][rr] + red[2][rr] + red[3][rr];
            ev[i][p] = __expf(vu) * mask[row0 + rr];
        }
    if (tid < ROWS) {
        const float vu = red[0][tid] + red[1][tid] + red[2][tid] + red[3][tid];
        e_out[row0 + tid] = __expf(vu) * mask[row0 + tid];
    }

    // ---- GEMM2: vuo = v @ Uo  (accumulates into the SAME acc array -> AGPR reuse)
#pragma unroll
    for (int i = 0; i < 2; ++i)
#pragma unroll
        for (int j = 0; j < 4; ++j) acc[i][j] = (f32x4){0.f, 0.f, 0.f, 0.f};
#pragma unroll
    for (int kk = 0; kk < 8; ++kk) {
        bf16x8 a[2], b[4];
#pragma unroll
        for (int i = 0; i < 2; ++i)
            a[i] = *(const bf16x8*)(xs + (i * 16 + c) * XP + kk * 32 + quad * 8);
#pragma unroll
        for (int j = 0; j < 4; ++j)
            b[j] = Uf8[(kk * 16 + w * 4 + j) * 64 + lane];
#pragma unroll
        for (int i = 0; i < 2; ++i)
#pragma unroll
            for (int j = 0; j < 4; ++j)
                acc[i][j] = __builtin_amdgcn_mfma_f32_16x16x32_bf16(a[i], b[j], acc[i][j], 0, 0, 0);
    }

    // betas numerator: exp(vuo*mask)*mask  (no max shift: |vuo| <= ~10, cancels exactly)
    float mk[2][4];
#pragma unroll
    for (int i = 0; i < 2; ++i)
#pragma unroll
        for (int r = 0; r < 4; ++r) mk[i][r] = mask[row0 + i * 16 + quad * 4 + r];
#pragma unroll
    for (int i = 0; i < 2; ++i)
#pragma unroll
        for (int j = 0; j < 4; ++j)
#pragma unroll
            for (int r = 0; r < 4; ++r) {
                const float t = acc[i][j][r] * mk[i][r];
                acc[i][j][r] = __expf(t) * mk[i][r];
            }
    // row sums
    float psum[2][4];
#pragma unroll
    for (int i = 0; i < 2; ++i)
#pragma unroll
        for (int r = 0; r < 4; ++r) {
            float s = 0.f;
#pragma unroll
            for (int j = 0; j < 4; ++j) s += acc[i][j][r];
            psum[i][r] = s;
        }
    __syncthreads();                                   // (d') ev/red reads + GEMM2 xs reads done
    {
        float myv = 0.f;
#pragma unroll
        for (int i = 0; i < 2; ++i)
#pragma unroll
            for (int r = 0; r < 4; ++r) {
                const float p = qred_add(psum[i][r]);
                if (c == i * 4 + r) myv = p;
            }
        if (c < 8) red[w][(c >> 2) * 16 + quad * 4 + (c & 3)] = myv;
    }
    __syncthreads();                                   // (e') beta sums in red

    // rs in store mapping
    float rs[2][4];
#pragma unroll
    for (int i = 0; i < 2; ++i)
#pragma unroll
        for (int p = 0; p < 4; ++p) {
            const int rr = i * 16 + hi + p * 4;
            const float s = red[0][rr] + red[1][rr] + red[2][rr] + red[3][rr];
            rs[i][p] = 1.f / ((s == 0.f) ? 1.f : s);
        }

    // ---- epilogue: LDS transpose (wave-private slice) -> coalesced float4 stores,
    //      fused out-partials with coalesced masked x re-read.
    float* tw = trans + w * (16 * TP);
    f32x4 opart = (f32x4){0.f, 0.f, 0.f, 0.f};
#pragma unroll
    for (int i = 0; i < 2; ++i) {
        asm volatile("s_waitcnt lgkmcnt(0)" ::: "memory");  // prior trans reads drained (WAR)
#pragma unroll
        for (int j = 0; j < 4; ++j)
#pragma unroll
            for (int r = 0; r < 4; ++r)
                tw[(quad * 4 + r) * TP + j * 16 + c] = acc[i][j][r];
        asm volatile("s_waitcnt lgkmcnt(0)" ::: "memory");  // writes visible (RAW)
#pragma unroll
        for (int p = 0; p < 4; ++p) {
            const int rl = hi + p * 4;                      // local row 0..15
            f32x4 b4 = *(const f32x4*)&tw[rl * TP + c4 * 4];
            const float rsv = rs[i][p];
            b4[0] *= rsv; b4[1] *= rsv; b4[2] *= rsv; b4[3] *= rsv;
            const size_t goff = (size_t)(row0 + i * 16 + rl) * D_ + w * 64 + c4 * 4;
            __builtin_nontemporal_store(b4, (f32x4*)&betas[goff]); // never re-read: keep L2 for x
            const float evv = ev[i][p];
            if (evv != 0.f) {                               // 16-lane-uniform skip
                const f32x4 x4 = *(const f32x4*)&x[goff];
                opart[0] += evv * b4[0] * x4[0];
                opart[1] += evv * b4[1] * x4[1];
                opart[2] += evv * b4[2] * x4[2];
                opart[3] += evv * b4[3] * x4[3];
            }
        }
    }
    // reduce across the 4 row-groups
#pragma unroll
    for (int k = 0; k < 4; ++k) {
        opart[k] += __shfl_xor(opart[k], 16);
        opart[k] += __shfl_xor(opart[k], 32);
    }
    if (lane < 16) {
        const int col = w * 64 + c4 * 4;
        if (use_part) {
            *(f32x4*)&part[(size_t)blockIdx.x * D_ + col] = opart;
        } else {
            const int b = row0 >> 10;
#pragma unroll
            for (int k = 0; k < 4; ++k) atomicAdd(&outraw[b * D_ + col + k], opart[k]);
        }
    }
}

// ---- final: Z per batch, normalize alphas in place, reduce out partials.
__global__ __launch_bounds__(256) void k_fin(
    const float* __restrict__ part, float* __restrict__ e_alphas,
    float* __restrict__ out, const int use_part)
{
    const int b = blockIdx.x;
    const int tid = threadIdx.x, lane = tid & 63, wid = tid >> 6;
    __shared__ float red[4];
    const int base = b * S_;
    float ev[4];
#pragma unroll
    for (int k = 0; k < 4; ++k) ev[k] = e_alphas[base + tid + 256 * k];
    float s = ev[0] + ev[1] + ev[2] + ev[3];
    s = wred_add(s);
    if (lane == 0) red[wid] = s;
    __syncthreads();
    const float Z = red[0] + red[1] + red[2] + red[3];
    const float Zr = 1.f / ((Z == 0.f) ? 1.f : Z);
#pragma unroll
    for (int k = 0; k < 4; ++k) e_alphas[base + tid + 256 * k] = ev[k] * Zr;

    float acc;
    if (use_part) {
        acc = 0.f;
#pragma unroll
        for (int k = 0; k < 32; ++k) acc += part[(size_t)(b * 32 + k) * D_ + tid];
    } else {
        acc = out[b * D_ + tid];
    }
    out[b * D_ + tid] = acc * Zr;
}

extern "C" void kernel_launch(void* const* d_in, const int* in_sizes, int n_in,
                              void* d_out, int out_size, void* d_ws, size_t ws_size,
                              hipStream_t stream) {
    const float* x    = (const float*)d_in[0];
    const float* mask = (const float*)d_in[1];
    const float* W    = (const float*)d_in[2];
    const float* bo   = (const float*)d_in[3];
    const float* u    = (const float*)d_in[4];
    const float* Uo   = (const float*)d_in[5];

    float* out    = (float*)d_out;             // [B, 256]
    float* alphas = out + B_ * D_;             // [B, S]
    float* betas  = alphas + (size_t)B_ * S_;  // [B, S, 256]

    __bf16* Wf = (__bf16*)d_ws;                // 128 KB
    __bf16* Uf = Wf + 65536;                   // 128 KB
    float* part = (float*)(Uf + 65536);        // 4096*256*4 = 4 MB (if it fits)

    const int nblk = B_ * S_ / ROWS;           // 4096
    const size_t need = 2 * 65536 * sizeof(__bf16) + (size_t)nblk * D_ * sizeof(float);
    const int use_part = (ws_size >= need) ? 1 : 0;

    if (!use_part)
        hipMemsetAsync(out, 0, (size_t)B_ * D_ * sizeof(float), stream);
    k_prep<<<256, 256, 0, stream>>>(W, Uo, Wf, Uf);
    k_rows<<<nblk, 256, 0, stream>>>(x, mask, Wf, bo, u, Uf, alphas, betas, part, out, use_part);
    k_fin <<<B_,   256, 0, stream>>>(part, alphas, out, use_part);
}

// Round 4
// 104.603 us; speedup vs baseline: 1.1703x; 1.1703x over previous
//
#include <hip/hip_runtime.h>
#include <math.h>

#define B_ 128
#define S_ 1024
#define D_ 256          // D == A == O == 256
#define XP 264          // LDS bf16 row pitch for x/v tile (528 B, 16B-aligned)
#define TP 68           // LDS fp32 row pitch for transpose buffer (272 B, 16B-aligned)
#define ROWS 32         // rows per block

using bf16x8 = __attribute__((ext_vector_type(8))) __bf16;
using bf16x4 = __attribute__((ext_vector_type(4))) __bf16;
using f32x4  = __attribute__((ext_vector_type(4))) float;

__device__ __forceinline__ float qred_add(float v) {   // reduce across 16-lane group
    v += __shfl_xor(v, 1); v += __shfl_xor(v, 2);
    v += __shfl_xor(v, 4); v += __shfl_xor(v, 8);
    return v;
}
__device__ __forceinline__ float wred_add(float x) {
#pragma unroll
    for (int off = 32; off > 0; off >>= 1) x += __shfl_xor(x, off, 64);
    return x;
}

// ---- prep: pack W, Uo (fp32 row-major [k][n]) into B-fragment-linear bf16.
__global__ __launch_bounds__(256) void k_prep(
    const float* __restrict__ W, const float* __restrict__ Uo,
    __bf16* __restrict__ Wf, __bf16* __restrict__ Uf)
{
    const int e = blockIdx.x * 256 + threadIdx.x;   // 0..65535
    const int frag = e >> 9, rem = e & 511;
    const int lane = rem >> 3, j = rem & 7;
    const int kk = frag >> 4, tn = frag & 15;
    const int k = kk * 32 + (lane >> 4) * 8 + j;
    const int n = tn * 16 + (lane & 15);
    Wf[e] = (__bf16)W[k * 256 + n];
    Uf[e] = (__bf16)Uo[k * 256 + n];
}

// ---- main fused kernel: 32 rows/block, 4 waves; wave w owns cols [64w, 64w+64).
// (256,3): round-3 showed (256,4)'s 128-cap splits 64V/64A and spills the ~80-reg
// VGPR set (+74 MB scratch writes). Budget 170 avoids that; acc-reuse keeps AGPR
// demand at 32 so if actual usage lands <=128 the HW schedules 4 blocks/CU anyway.
// Barriers cut 6 -> 4: vu partials go to red2 BEFORE barrier (b) (which already
// orders v-tile writes); beta row-sums go to red BEFORE barrier (d) (which
// already orders GEMM2 xs reads vs aliasing transpose writes).
__global__ __launch_bounds__(256, 3) void k_rows(
    const float* __restrict__ x, const float* __restrict__ mask,
    const __bf16* __restrict__ Wf, const float* __restrict__ bo,
    const float* __restrict__ u, const __bf16* __restrict__ Uf,
    float* __restrict__ e_out,    // [B*S] unnormalized exp(vu)*mask (alphas region)
    float* __restrict__ betas,    // [B*S, 256]
    float* __restrict__ part,     // [gridDim.x, 256] per-block out partials (ws)
    float* __restrict__ outraw,   // [B,256] atomic fallback accumulator
    const int use_part)
{
    // xs (bf16 x/v tile, 16896 B) aliased with trans (fp32 transpose buf, 17408 B)
    __shared__ __align__(16) char smem[4 * 16 * TP * 4];
    __bf16* xs   = (__bf16*)smem;
    float* trans = (float*)smem;
    __shared__ float red[4][ROWS];    // ||t||^2 partials, then beta row-sum partials
    __shared__ float red2[4][ROWS];   // vu partials
    const int tid = threadIdx.x, lane = tid & 63, w = tid >> 6;
    const int quad = lane >> 4, c = lane & 15;
    const int hi = lane >> 4, c4 = lane & 15;      // store-phase decomposition
    const int row0 = blockIdx.x * ROWS;
    const bf16x8* Wf8 = (const bf16x8*)Wf;
    const bf16x8* Uf8 = (const bf16x8*)Uf;

    // stage x[32][256] fp32 -> bf16 LDS
    {
        const float4* xg = (const float4*)(x + (size_t)row0 * D_);
#pragma unroll
        for (int it = 0; it < 8; ++it) {
            const int r = it * 4 + w;
            const float4 t = xg[r * 64 + lane];
            bf16x4 h; h[0] = (__bf16)t.x; h[1] = (__bf16)t.y; h[2] = (__bf16)t.z; h[3] = (__bf16)t.w;
            *(bf16x4*)(xs + r * XP + lane * 4) = h;
        }
    }

    __syncthreads();                                   // sync0: x staged

    // ---- GEMM1: t = x @ W
    f32x4 acc[2][4];                                   // reused by GEMM2 (32 AGPR total)
#pragma unroll
    for (int i = 0; i < 2; ++i)
#pragma unroll
        for (int j = 0; j < 4; ++j) acc[i][j] = (f32x4){0.f, 0.f, 0.f, 0.f};
#pragma unroll
    for (int kk = 0; kk < 8; ++kk) {
        bf16x8 a[2], b[4];
#pragma unroll
        for (int i = 0; i < 2; ++i)
            a[i] = *(const bf16x8*)(xs + (i * 16 + c) * XP + kk * 32 + quad * 8);
#pragma unroll
        for (int j = 0; j < 4; ++j)
            b[j] = Wf8[(kk * 16 + w * 4 + j) * 64 + lane];
#pragma unroll
        for (int i = 0; i < 2; ++i)
#pragma unroll
            for (int j = 0; j < 4; ++j)
                acc[i][j] = __builtin_amdgcn_mfma_f32_16x16x32_bf16(a[i], b[j], acc[i][j], 0, 0, 0);
    }

    // bias + row sum-of-squares partials
#pragma unroll
    for (int j = 0; j < 4; ++j) {
        const float bj = bo[w * 64 + j * 16 + c];
#pragma unroll
        for (int i = 0; i < 2; ++i)
#pragma unroll
            for (int r = 0; r < 4; ++r) acc[i][j][r] += bj;
    }
    {
        float myv = 0.f;
#pragma unroll
        for (int i = 0; i < 2; ++i)
#pragma unroll
            for (int r = 0; r < 4; ++r) {
                float s = 0.f;
#pragma unroll
                for (int j = 0; j < 4; ++j) s += acc[i][j][r] * acc[i][j][r];
                const float p = qred_add(s);
                if (c == i * 4 + r) myv = p;
            }
        if (c < 8) red[w][(c >> 2) * 16 + quad * 4 + (c & 3)] = myv;
    }
    __syncthreads();                                   // (a): norm partials visible;
                                                       //      also GEMM1 xs reads done (v-write WAR)

    float inv[2][4];
#pragma unroll
    for (int i = 0; i < 2; ++i)
#pragma unroll
        for (int r = 0; r < 4; ++r) {
            const int row = i * 16 + quad * 4 + r;
            const float t = red[0][row] + red[1][row] + red[2][row] + red[3][row];
            inv[i][r] = 1.f / fmaxf(sqrtf(t), 1e-12f);
        }

    // v = tanh(t/||t||): vu partials, write v (bf16) into xs (reuse).
    // LAST read of GEMM1's acc -- dead after this loop (enables AGPR reuse).
    float uj[4];
#pragma unroll
    for (int j = 0; j < 4; ++j) uj[j] = u[w * 64 + j * 16 + c];
    float vup[2][4];
#pragma unroll
    for (int i = 0; i < 2; ++i)
#pragma unroll
        for (int r = 0; r < 4; ++r) vup[i][r] = 0.f;
#pragma unroll
    for (int i = 0; i < 2; ++i)
#pragma unroll
        for (int j = 0; j < 4; ++j)
#pragma unroll
            for (int r = 0; r < 4; ++r) {
                const float tv = acc[i][j][r] * inv[i][r];
                const float e2 = __expf(2.f * tv);
                const float v  = (e2 - 1.f) * __frcp_rn(e2 + 1.f);
                vup[i][r] += v * uj[j];
                xs[(i * 16 + quad * 4 + r) * XP + (w * 64 + j * 16 + c)] = (__bf16)v;
            }
    // vu partials into red2 BEFORE the barrier (red2 has no prior readers).
    {
        float myv = 0.f;
#pragma unroll
        for (int i = 0; i < 2; ++i)
#pragma unroll
            for (int r = 0; r < 4; ++r) {
                const float p = qred_add(vup[i][r]);
                if (c == i * 4 + r) myv = p;
            }
        if (c < 8) red2[w][(c >> 2) * 16 + quad * 4 + (c & 3)] = myv;
    }
    __syncthreads();                                   // (b): v tile AND vu partials visible

    // ev in store mapping: row r_ip = i*16 + hi + p*4
    float ev[2][4];
#pragma unroll
    for (int i = 0; i < 2; ++i)
#pragma unroll
        for (int p = 0; p < 4; ++p) {
            const int rr = i * 16 + hi + p * 4;
            const float vu = red2[0][rr] + red2[1][rr] + red2[2][rr] + red2[3][rr];
            ev[i][p] = __expf(vu) * mask[row0 + rr];
        }
    if (tid < ROWS) {
        const float vu = red2[0][tid] + red2[1][tid] + red2[2][tid] + red2[3][tid];
        e_out[row0 + tid] = __expf(vu) * mask[row0 + tid];
    }

    // ---- GEMM2: vuo = v @ Uo  (accumulates into the SAME acc array -> AGPR reuse)
#pragma unroll
    for (int i = 0; i < 2; ++i)
#pragma unroll
        for (int j = 0; j < 4; ++j) acc[i][j] = (f32x4){0.f, 0.f, 0.f, 0.f};
#pragma unroll
    for (int kk = 0; kk < 8; ++kk) {
        bf16x8 a[2], b[4];
#pragma unroll
        for (int i = 0; i < 2; ++i)
            a[i] = *(const bf16x8*)(xs + (i * 16 + c) * XP + kk * 32 + quad * 8);
#pragma unroll
        for (int j = 0; j < 4; ++j)
            b[j] = Uf8[(kk * 16 + w * 4 + j) * 64 + lane];
#pragma unroll
        for (int i = 0; i < 2; ++i)
#pragma unroll
            for (int j = 0; j < 4; ++j)
                acc[i][j] = __builtin_amdgcn_mfma_f32_16x16x32_bf16(a[i], b[j], acc[i][j], 0, 0, 0);
    }

    // betas numerator: exp(vuo*mask)*mask  (no max shift: |vuo| <= ~10, cancels exactly)
    float mk[2][4];
#pragma unroll
    for (int i = 0; i < 2; ++i)
#pragma unroll
        for (int r = 0; r < 4; ++r) mk[i][r] = mask[row0 + i * 16 + quad * 4 + r];
#pragma unroll
    for (int i = 0; i < 2; ++i)
#pragma unroll
        for (int j = 0; j < 4; ++j)
#pragma unroll
            for (int r = 0; r < 4; ++r) {
                const float t = acc[i][j][r] * mk[i][r];
                acc[i][j][r] = __expf(t) * mk[i][r];
            }
    // beta row-sum partials into red BEFORE the barrier (red's last reader was
    // inv, pre-(b): no WAR hazard).
    {
        float myv = 0.f;
#pragma unroll
        for (int i = 0; i < 2; ++i)
#pragma unroll
            for (int r = 0; r < 4; ++r) {
                float s = 0.f;
#pragma unroll
                for (int j = 0; j < 4; ++j) s += acc[i][j][r];
                const float p = qred_add(s);
                if (c == i * 4 + r) myv = p;
            }
        if (c < 8) red[w][(c >> 2) * 16 + quad * 4 + (c & 3)] = myv;
    }
    __syncthreads();                                   // (d): GEMM2 xs reads done (trans-write WAR)
                                                       //      AND beta sums visible

    // rs in store mapping
    float rs[2][4];
#pragma unroll
    for (int i = 0; i < 2; ++i)
#pragma unroll
        for (int p = 0; p < 4; ++p) {
            const int rr = i * 16 + hi + p * 4;
            const float s = red[0][rr] + red[1][rr] + red[2][rr] + red[3][rr];
            rs[i][p] = 1.f / ((s == 0.f) ? 1.f : s);
        }

    // ---- epilogue: LDS transpose (wave-private slice) -> coalesced float4 stores,
    //      fused out-partials with coalesced masked x re-read.
    float* tw = trans + w * (16 * TP);
    f32x4 opart = (f32x4){0.f, 0.f, 0.f, 0.f};
#pragma unroll
    for (int i = 0; i < 2; ++i) {
        asm volatile("s_waitcnt lgkmcnt(0)" ::: "memory");  // prior trans reads drained (WAR)
#pragma unroll
        for (int j = 0; j < 4; ++j)
#pragma unroll
            for (int r = 0; r < 4; ++r)
                tw[(quad * 4 + r) * TP + j * 16 + c] = acc[i][j][r];
        asm volatile("s_waitcnt lgkmcnt(0)" ::: "memory");  // writes visible (RAW)
#pragma unroll
        for (int p = 0; p < 4; ++p) {
            const int rl = hi + p * 4;                      // local row 0..15
            f32x4 b4 = *(const f32x4*)&tw[rl * TP + c4 * 4];
            const float rsv = rs[i][p];
            b4[0] *= rsv; b4[1] *= rsv; b4[2] *= rsv; b4[3] *= rsv;
            const size_t goff = (size_t)(row0 + i * 16 + rl) * D_ + w * 64 + c4 * 4;
            __builtin_nontemporal_store(b4, (f32x4*)&betas[goff]); // never re-read: keep L2 for x
            const float evv = ev[i][p];
            if (evv != 0.f) {                               // 16-lane-uniform skip
                const f32x4 x4 = *(const f32x4*)&x[goff];
                opart[0] += evv * b4[0] * x4[0];
                opart[1] += evv * b4[1] * x4[1];
                opart[2] += evv * b4[2] * x4[2];
                opart[3] += evv * b4[3] * x4[3];
            }
        }
    }
    // reduce across the 4 row-groups
#pragma unroll
    for (int k = 0; k < 4; ++k) {
        opart[k] += __shfl_xor(opart[k], 16);
        opart[k] += __shfl_xor(opart[k], 32);
    }
    if (lane < 16) {
        const int col = w * 64 + c4 * 4;
        if (use_part) {
            *(f32x4*)&part[(size_t)blockIdx.x * D_ + col] = opart;
        } else {
            const int b = row0 >> 10;
#pragma unroll
            for (int k = 0; k < 4; ++k) atomicAdd(&outraw[b * D_ + col + k], opart[k]);
        }
    }
}

// ---- final: Z per batch, normalize alphas in place, reduce out partials.
__global__ __launch_bounds__(256) void k_fin(
    const float* __restrict__ part, float* __restrict__ e_alphas,
    float* __restrict__ out, const int use_part)
{
    const int b = blockIdx.x;
    const int tid = threadIdx.x, lane = tid & 63, wid = tid >> 6;
    __shared__ float red[4];
    const int base = b * S_;
    float ev[4];
#pragma unroll
    for (int k = 0; k < 4; ++k) ev[k] = e_alphas[base + tid + 256 * k];
    float s = ev[0] + ev[1] + ev[2] + ev[3];
    s = wred_add(s);
    if (lane == 0) red[wid] = s;
    __syncthreads();
    const float Z = red[0] + red[1] + red[2] + red[3];
    const float Zr = 1.f / ((Z == 0.f) ? 1.f : Z);
#pragma unroll
    for (int k = 0; k < 4; ++k) e_alphas[base + tid + 256 * k] = ev[k] * Zr;

    float acc;
    if (use_part) {
        acc = 0.f;
#pragma unroll
        for (int k = 0; k < 32; ++k) acc += part[(size_t)(b * 32 + k) * D_ + tid];
    } else {
        acc = out[b * D_ + tid];
    }
    out[b * D_ + tid] = acc * Zr;
}

extern "C" void kernel_launch(void* const* d_in, const int* in_sizes, int n_in,
                              void* d_out, int out_size, void* d_ws, size_t ws_size,
                              hipStream_t stream) {
    const float* x    = (const float*)d_in[0];
    const float* mask = (const float*)d_in[1];
    const float* W    = (const float*)d_in[2];
    const float* bo   = (const float*)d_in[3];
    const float* u    = (const float*)d_in[4];
    const float* Uo   = (const float*)d_in[5];

    float* out    = (float*)d_out;             // [B, 256]
    float* alphas = out + B_ * D_;             // [B, S]
    float* betas  = alphas + (size_t)B_ * S_;  // [B, S, 256]

    __bf16* Wf = (__bf16*)d_ws;                // 128 KB
    __bf16* Uf = Wf + 65536;                   // 128 KB
    float* part = (float*)(Uf + 65536);        // 4096*256*4 = 4 MB (if it fits)

    const int nblk = B_ * S_ / ROWS;           // 4096
    const size_t need = 2 * 65536 * sizeof(__bf16) + (size_t)nblk * D_ * sizeof(float);
    const int use_part = (ws_size >= need) ? 1 : 0;

    if (!use_part)
        hipMemsetAsync(out, 0, (size_t)B_ * D_ * sizeof(float), stream);
    k_prep<<<256, 256, 0, stream>>>(W, Uo, Wf, Uf);
    k_rows<<<nblk, 256, 0, stream>>>(x, mask, Wf, bo, u, Uf, alphas, betas, part, out, use_part);
    k_fin <<<B_,   256, 0, stream>>>(part, alphas, out, use_part);
}